// Round 1
// baseline (778.809 us; speedup 1.0000x reference)
//
#include <hip/hip_runtime.h>

// Fused SIREN INR round 7. r6 base (TOK=128, 512 thr, fragment-ordered
// weights, chunk-major LDS) + TOKEN-SPLIT SOFTWARE PIPELINE:
// each layer becomes two stages over token halves A (0..63) / B (64..127):
//   stage: MFMA(half, layer k)  ||  sine-epilogue(other half, layer k-1)
// so the sine VALU work (30% of time, previously serialized between
// barriers) executes under the MFMA pipe. One barrier per stage (same
// total count). Epi writes tokens of prevHalf; concurrent b-reads touch
// tokens of half -> disjoint LDS, race-free.
// Cost accepted: a-frags fetched twice/layer (2nd pass L2-hit), a:MFMA
// ratio 1:4 with 1-deep a-prefetch (620cyc window >> 225cyc L2 hit).
// Register budget: accA+accB = 128 (same as old acc[4][8]); a-prefetch
// reduced 3-buf -> 2-buf to stay <=256 total regs (2 waves/SIMD).

#define L_TOTAL 262144
#define TOK 128
#define THREADS 512
#define C_SC 4.77464829275686f  // 30/(2*pi)

typedef _Float16 f16x8 __attribute__((ext_vector_type(8)));
typedef _Float16 f16x4 __attribute__((ext_vector_type(4)));
typedef float    f32x4 __attribute__((ext_vector_type(4)));

#define N1 (512 * 256)                 // W_first elems
#define N2 (N1 + 5 * 512 * 512)        // + W_hidden
#define N3 (N2 + 16 * 512)             // + W_out padded to 16 rows
#define NBIAS 3072                     // 512 first + 5*512 hidden (pre-scaled)

// Fragment-ordered destination for first+hidden weights:
// dst[((mt*KS + ks)*64 + lane)*8 + e] = W[row=mt*16+(lane&15)]
//                                        [col=ks*32+(lane>>4)*8+e]
__global__ void convert_weights(const float* __restrict__ Wf,
                                const float* __restrict__ Wh,
                                const float* __restrict__ Wo,
                                const float* __restrict__ bf,
                                const float* __restrict__ bh,
                                _Float16* __restrict__ o,
                                float* __restrict__ biasC) {
  int i = blockIdx.x * blockDim.x + threadIdx.x;
  if (i < N3) {
    float v;
    if (i < N1) {                      // first layer: 512x256, KS=8
      const int blk = i >> 9, w = i & 511;
      const int lane = w >> 3, e = w & 7;
      const int mt = blk >> 3, ks = blk & 7;
      const int row = mt * 16 + (lane & 15);
      const int col = ks * 32 + (lane >> 4) * 8 + e;
      v = Wf[row * 256 + col];
    } else if (i < N2) {               // hidden: 5 x 512x512, KS=16
      int j = i - N1;
      const int l = j >> 18;
      j &= (1 << 18) - 1;
      const int blk = j >> 9, w = j & 511;
      const int lane = w >> 3, e = w & 7;
      const int mt = blk >> 4, ks = blk & 15;
      const int row = mt * 16 + (lane & 15);
      const int col = ks * 32 + (lane >> 4) * 8 + e;
      v = Wh[l * (512 * 512) + row * 512 + col];
    } else {                           // out layer: row-major, padded 16x512
      const int r = (i - N2) >> 9, c = (i - N2) & 511;
      v = (r < 3) ? Wo[r * 512 + c] : 0.0f;
    }
    o[i] = (_Float16)v;
  } else if (i < N3 + NBIAS) {
    int j = i - N3;
    biasC[j] = (j < 512 ? bf[j] : bh[j - 512]) * C_SC;
  }
}

// h LDS layout: elem addr = (chunk*128 + token)*8 + (f&7), chunk = f>>3.
__device__ __forceinline__ int h_elem(int chunk, int token) {
  return (chunk * 128 + token) * 8;
}

// Standalone epilogue: h[prevHalf tokens] <- sin(30*(acc + b)).
__device__ __forceinline__ void sine_epi(const float* __restrict__ biasEpi,
                                         _Float16* hb, int lr, int lg, int m0,
                                         int prevHalf, f32x4 (&accPrev)[4][4]) {
#pragma unroll
  for (int mt = 0; mt < 4; ++mt) {
    const int ob = m0 + mt * 16 + lg * 4;
    const f32x4 bb = *(const f32x4*)&biasEpi[ob];
    const int wbase = (ob >> 3) * 128 * 8 + (ob & 7);
#pragma unroll
    for (int nt = 0; nt < 4; ++nt) {
      f16x4 hv;
#pragma unroll
      for (int r = 0; r < 4; ++r) {
        float pre = fmaf(accPrev[mt][nt][r], C_SC, bb[r]);  // revolutions
        hv[r] = (_Float16)__builtin_amdgcn_sinf(__builtin_amdgcn_fractf(pre));
      }
      *(f16x4*)&hb[wbase + (prevHalf * 64 + nt * 16 + lr) * 8] = hv;
    }
  }
}

// One pipeline stage: MFMA K-loop for 4 nt tiles (tokens half*64..+63)
// with the previous acc's sine epilogue interleaved one output per k-step.
// W is fragment-ordered. No barrier inside; caller syncs between stages.
template <int K, bool EPI>
__device__ __forceinline__ void sine_stage(
    const _Float16* __restrict__ W, const float* __restrict__ biasEpi,
    _Float16* hb, int lane, int lr, int lg, int m0, int half, int prevHalf,
    f32x4 (&acc)[4][4], f32x4 (&accPrev)[4][4]) {
  constexpr int KS = K / 32;
  constexpr int EPO = 16 / KS;  // epi outputs per k-step (1 hidden, 2 first)

#pragma unroll
  for (int mt = 0; mt < 4; ++mt)
#pragma unroll
    for (int nt = 0; nt < 4; ++nt)
      acc[mt][nt] = (f32x4){0.f, 0.f, 0.f, 0.f};

  // per-mt fragment-ordered base: one contiguous 1KB burst per (mt, ks)
  const _Float16* wb[4];
#pragma unroll
  for (int mt = 0; mt < 4; ++mt)
    wb[mt] = &W[(((m0 >> 4) + mt) * KS) * 512 + lane * 8];

  f32x4 bb[4];
  if constexpr (EPI) {
#pragma unroll
    for (int mt = 0; mt < 4; ++mt)
      bb[mt] = *(const f32x4*)&biasEpi[m0 + mt * 16 + lg * 4];
  }

  f16x8 a[2][4], b[2][4];
#pragma unroll
  for (int mt = 0; mt < 4; ++mt) a[0][mt] = *(const f16x8*)(wb[mt]);
#pragma unroll
  for (int nt = 0; nt < 4; ++nt)
    b[0][nt] = *(const f16x8*)&hb[h_elem(lg, half * 64 + nt * 16 + lr)];

#pragma unroll
  for (int ks = 0; ks < KS; ++ks) {
    const int cur = ks & 1;
    if (ks + 1 < KS) {  // prefetch next k-step's b-frags + a-frags
#pragma unroll
      for (int nt = 0; nt < 4; ++nt)
        b[cur ^ 1][nt] = *(const f16x8*)&hb[h_elem((ks + 1) * 4 + lg,
                                                   half * 64 + nt * 16 + lr)];
#pragma unroll
      for (int mt = 0; mt < 4; ++mt)
        a[cur ^ 1][mt] = *(const f16x8*)(wb[mt] + (ks + 1) * 512);
    }
    if constexpr (EPI) {  // one (mt,nt) slice of prev-half epilogue per ks
#pragma unroll
      for (int u = 0; u < EPO; ++u) {
        const int idx = ks * EPO + u;
        const int mt = idx >> 2, nt = idx & 3;
        const int ob = m0 + mt * 16 + lg * 4;
        f16x4 hv;
#pragma unroll
        for (int r = 0; r < 4; ++r) {
          float pre = fmaf(accPrev[mt][nt][r], C_SC, bb[mt][r]);
          hv[r] = (_Float16)__builtin_amdgcn_sinf(__builtin_amdgcn_fractf(pre));
        }
        const int wbase = (ob >> 3) * 128 * 8 + (ob & 7);
        *(f16x4*)&hb[wbase + (prevHalf * 64 + nt * 16 + lr) * 8] = hv;
      }
    }
#pragma unroll
    for (int mt = 0; mt < 4; ++mt)
#pragma unroll
      for (int nt = 0; nt < 4; ++nt)
        acc[mt][nt] = __builtin_amdgcn_mfma_f32_16x16x32_f16(
            a[cur][mt], b[cur][nt], acc[mt][nt], 0, 0, 0);
  }
}

__global__ __launch_bounds__(THREADS, 2) void siren_kernel(
    const float* __restrict__ coords, const float* __restrict__ bff,
    const float* __restrict__ biasC, const float* __restrict__ b_out,
    const _Float16* __restrict__ wf, const _Float16* __restrict__ wh,
    const _Float16* __restrict__ wo, float* __restrict__ out) {
  extern __shared__ _Float16 hb[];  // chunk-major: [64 chunks][128 tok][8]
  const int tid = threadIdx.x;
  const int t0 = blockIdx.x * TOK;

  // ---- Fourier features: chunks q*4+cb (sin), 16+q*4+cb (cos) ----
  {
    const int t = tid & 127;   // token (wave = 64 consecutive tokens)
    const int q = tid >> 7;    // feature octant: proj j in [q*32, q*32+32)
    const float c0 = coords[(t0 + t) * 3 + 0];
    const float c1 = coords[(t0 + t) * 3 + 1];
    const float c2 = coords[(t0 + t) * 3 + 2];
#pragma unroll
    for (int cb = 0; cb < 4; ++cb) {
      f16x8 sv, cv;
#pragma unroll
      for (int e = 0; e < 8; ++e) {
        const int j = q * 32 + cb * 8 + e;
        float r = fmaf(c0, bff[j], fmaf(c1, bff[128 + j], c2 * bff[256 + j]));
        float fr = __builtin_amdgcn_fractf(r);
        sv[e] = (_Float16)__builtin_amdgcn_sinf(fr);
        cv[e] = (_Float16)__builtin_amdgcn_cosf(fr);
      }
      *(f16x8*)&hb[h_elem(q * 4 + cb, t)] = sv;        // lane-linear store
      *(f16x8*)&hb[h_elem(16 + q * 4 + cb, t)] = cv;
    }
  }
  __syncthreads();

  const int lane = tid & 63;
  const int lr = lane & 15;   // A: weight row / B: token / C: token col
  const int lg = lane >> 4;   // k-group for frags, row-group for C
  const int m0 = (tid >> 6) * 64;  // wave's 64-feature output slice

  f32x4 accA[4][4], accB[4][4];

  // Pipeline: stage = MFMA(half, Lk) || sine(other half, Lk-1)
  sine_stage<256, false>(wf, nullptr, hb, lane, lr, lg, m0, 0, 0, accA, accB);
  __syncthreads();
  sine_stage<256, true>(wf, biasC, hb, lane, lr, lg, m0, 1, 0, accB, accA);
  __syncthreads();
#pragma unroll 1
  for (int l = 0; l < 5; ++l) {
    const _Float16* Wl = wh + l * (512 * 512);
    const float* bPrev = (l == 0) ? biasC : biasC + 512 + (l - 1) * 512;
    sine_stage<512, true>(Wl, bPrev, hb, lane, lr, lg, m0, 0, 1, accA, accB);
    __syncthreads();
    sine_stage<512, true>(Wl, biasC + 512 + l * 512, hb, lane, lr, lg, m0, 1, 0,
                          accB, accA);
    __syncthreads();
  }
  sine_epi(biasC + 512 + 4 * 512, hb, lr, lg, m0, 1, accB);  // drain B(L6)
  __syncthreads();

  // ---- final linear: out[t][0..2], 16 tokens per wave, 8 waves ----
  {
    const int wave = tid >> 6;
    f32x4 acc = {0.f, 0.f, 0.f, 0.f};
#pragma unroll
    for (int ks = 0; ks < 16; ++ks) {
      f16x8 a = *(const f16x8*)&wo[lr * 512 + ks * 32 + lg * 8];
      f16x8 b = *(const f16x8*)&hb[h_elem(ks * 4 + lg, wave * 16 + lr)];
      acc = __builtin_amdgcn_mfma_f32_16x16x32_f16(a, b, acc, 0, 0, 0);
    }
    if (lg == 0) {  // C rows 0..3 in lanes 0..15; out-feature = reg idx
      const int t = t0 + wave * 16 + lr;
      out[t * 3 + 0] = acc[0] + b_out[0];
      out[t * 3 + 1] = acc[1] + b_out[1];
      out[t * 3 + 2] = acc[2] + b_out[2];
    }
  }
}

extern "C" void kernel_launch(void* const* d_in, const int* in_sizes, int n_in,
                              void* d_out, int out_size, void* d_ws,
                              size_t ws_size, hipStream_t stream) {
  const float* coords = (const float*)d_in[0];
  const float* bff    = (const float*)d_in[1];
  const float* Wf     = (const float*)d_in[2];
  const float* bf     = (const float*)d_in[3];
  const float* Wh     = (const float*)d_in[4];
  const float* bh     = (const float*)d_in[5];
  const float* Wo     = (const float*)d_in[6];
  const float* bo     = (const float*)d_in[7];
  float* out = (float*)d_out;

  _Float16* w16 = (_Float16*)d_ws;
  float* biasC = (float*)(w16 + N3);  // 16B-aligned (N3*2 % 16 == 0)

  convert_weights<<<(N3 + NBIAS + 255) / 256, 256, 0, stream>>>(
      Wf, Wh, Wo, bf, bh, w16, biasC);

  const size_t lds_bytes = 64 * 128 * 8 * sizeof(_Float16);  // 131072
  siren_kernel<<<L_TOTAL / TOK, THREADS, lds_bytes, stream>>>(
      coords, bff, biasC, bo, w16, w16 + N1, w16 + N2, out);
}

// Round 2
// 767.335 us; speedup vs baseline: 1.0150x; 1.0150x over previous
//
#include <hip/hip_runtime.h>

// Fused SIREN INR round 8. Revert to r6 structure (TOK=128, 512 thr,
// fragment-ordered weights, chunk-major LDS, 2 barriers/layer, 2-deep
// a-prefetch, b double-buffer) + switch K-loop to 32x32x16 f16 MFMA
// (2178 TF ceiling vs 1955 for 16x16x32: +11% pipe rate, half the
// instruction count). Wave = 2 mt-tiles (32 feats) x 4 nt-tiles (32 tok).
// LOCKED LESSONS:
//  - 1x weight L2 traffic per CU is mandatory: r6 already streams 16 TB/s
//    aggregate L2->CU (47% of 34.5 TB/s ceiling). r7's token-split doubled
//    it to ~93% -> a-prefetch starvation ate the intended MFMA/VALU
//    overlap (dur 739->787, zero overlap gained). With TOK=128 pinned by
//    LDS (1 block/CU), full a-reuse requires all tokens per k-step ->
//    no independent VALU exists inside a layer's K-loop. Don't retry.
//  - >=8 MFMA per a-load in *traffic* terms (r2/r4/r5).

#define L_TOTAL 262144
#define TOK 128
#define THREADS 512
#define C_SC 4.77464829275686f  // 30/(2*pi)

typedef _Float16 f16x8 __attribute__((ext_vector_type(8)));
typedef _Float16 f16x4 __attribute__((ext_vector_type(4)));
typedef float    f32x4 __attribute__((ext_vector_type(4)));
typedef float    f32x16 __attribute__((ext_vector_type(16)));

#define N1 (512 * 256)                 // W_first elems
#define N2 (N1 + 5 * 512 * 512)        // + W_hidden
#define N3 (N2 + 16 * 512)             // + W_out padded to 16 rows
#define NBIAS 3072                     // 512 first + 5*512 hidden (pre-scaled)

// Fragment-ordered weights for 32x32x16 MFMA:
// dst[((mt*KS + ks)*64 + lane)*8 + e] = W[row = mt*32 + (lane&31)]
//                                        [col = ks*16 + (lane>>5)*8 + e]
// (A-frag: lane holds 8 consecutive k at fixed row; one contiguous 1KB
//  burst per (mt,ks) per wave.)
__global__ void convert_weights(const float* __restrict__ Wf,
                                const float* __restrict__ Wh,
                                const float* __restrict__ Wo,
                                const float* __restrict__ bf,
                                const float* __restrict__ bh,
                                _Float16* __restrict__ o,
                                float* __restrict__ biasC) {
  int i = blockIdx.x * blockDim.x + threadIdx.x;
  if (i < N3) {
    float v;
    if (i < N1) {                      // first layer: 512x256, KS=16
      const int blk = i >> 9, w = i & 511;
      const int lane = w >> 3, e = w & 7;
      const int mt = blk >> 4, ks = blk & 15;
      const int row = mt * 32 + (lane & 31);
      const int col = ks * 16 + (lane >> 5) * 8 + e;
      v = Wf[row * 256 + col];
    } else if (i < N2) {               // hidden: 5 x 512x512, KS=32
      int j = i - N1;
      const int l = j >> 18;
      j &= (1 << 18) - 1;
      const int blk = j >> 9, w = j & 511;
      const int lane = w >> 3, e = w & 7;
      const int mt = blk >> 5, ks = blk & 31;
      const int row = mt * 32 + (lane & 31);
      const int col = ks * 16 + (lane >> 5) * 8 + e;
      v = Wh[l * (512 * 512) + row * 512 + col];
    } else {                           // out layer: row-major, padded 16x512
      const int r = (i - N2) >> 9, c = (i - N2) & 511;
      v = (r < 3) ? Wo[r * 512 + c] : 0.0f;
    }
    o[i] = (_Float16)v;
  } else if (i < N3 + NBIAS) {
    int j = i - N3;
    biasC[j] = (j < 512 ? bf[j] : bh[j - 512]) * C_SC;
  }
}

// h LDS layout: elem addr = (chunk*128 + token)*8 + (f&7), chunk = f>>3.
// b-frag ds_read_b128 addr16B = chunk*128 + token: lane-linear.
__device__ __forceinline__ int h_elem(int chunk, int token) {
  return (chunk * 128 + token) * 8;
}

// One sine layer: h <- sin(30*(W h + b)). M=512 (8 waves x 64 feats as
// 2 x 32-row tiles), N=128 tokens (4 x 32-token tiles), K templated.
// 32x32x16 MFMA; W fragment-ordered (see convert_weights).
template <int K>
__device__ __forceinline__ void sine_layer(const _Float16* __restrict__ W,
                                           const float* __restrict__ biasC,
                                           _Float16* hb, int lane, int tk,
                                           int kg, int m0) {
  constexpr int KS = K / 16;
  f32x16 acc[2][4];
#pragma unroll
  for (int mt = 0; mt < 2; ++mt)
#pragma unroll
    for (int nt = 0; nt < 4; ++nt)
#pragma unroll
      for (int r = 0; r < 16; ++r) acc[mt][nt][r] = 0.f;

  // per-mt fragment-ordered base: one contiguous 1KB burst per (mt, ks)
  const _Float16* wb[2];
#pragma unroll
  for (int mt = 0; mt < 2; ++mt)
    wb[mt] = &W[(((m0 >> 5) + mt) * KS) * 512 + lane * 8];

  f16x8 a[3][2], b[2][4];
#pragma unroll
  for (int mt = 0; mt < 2; ++mt) a[0][mt] = *(const f16x8*)(wb[mt]);
#pragma unroll
  for (int mt = 0; mt < 2; ++mt) a[1][mt] = *(const f16x8*)(wb[mt] + 512);
#pragma unroll
  for (int nt = 0; nt < 4; ++nt)
    b[0][nt] = *(const f16x8*)&hb[h_elem(kg, nt * 32 + tk)];

#pragma unroll
  for (int ks = 0; ks < KS; ++ks) {
    const int cur = ks & 1;
    const int ai = ks % 3;
    if (ks + 1 < KS) {  // prefetch next k-step's b-frags under these MFMAs
#pragma unroll
      for (int nt = 0; nt < 4; ++nt)
        b[cur ^ 1][nt] =
            *(const f16x8*)&hb[h_elem((ks + 1) * 2 + kg, nt * 32 + tk)];
    }
    if (ks + 2 < KS) {  // 2-deep a-prefetch (~1000cyc cover >> L2 latency)
#pragma unroll
      for (int mt = 0; mt < 2; ++mt)
        a[(ks + 2) % 3][mt] = *(const f16x8*)(wb[mt] + (ks + 2) * 512);
    }
#pragma unroll
    for (int mt = 0; mt < 2; ++mt)
#pragma unroll
      for (int nt = 0; nt < 4; ++nt)
        acc[mt][nt] = __builtin_amdgcn_mfma_f32_32x32x16_f16(
            a[ai][mt], b[cur][nt], acc[mt][nt], 0, 0, 0);
  }
  __syncthreads();  // all reads of hb done before overwrite

  // Epilogue: C/D layout col=lane&31 (token), row=(r&3)+8*(r>>2)+4*kg.
  // reg quad q=r>>2 -> 4 consecutive feats at f0 = m0+mt*32+4*kg+8q.
#pragma unroll
  for (int mt = 0; mt < 2; ++mt) {
    const int cbase = (m0 >> 3) + mt * 4;  // h chunk base for this tile
    f32x4 bq[4];
#pragma unroll
    for (int q = 0; q < 4; ++q)
      bq[q] = *(const f32x4*)&biasC[m0 + mt * 32 + 4 * kg + 8 * q];
#pragma unroll
    for (int nt = 0; nt < 4; ++nt) {
      const int tok = nt * 32 + tk;
#pragma unroll
      for (int q = 0; q < 4; ++q) {
        f16x4 hv;
#pragma unroll
        for (int j = 0; j < 4; ++j) {
          float pre = fmaf(acc[mt][nt][q * 4 + j], C_SC, bq[q][j]);
          hv[j] = (_Float16)__builtin_amdgcn_sinf(__builtin_amdgcn_fractf(pre));
        }
        *(f16x4*)&hb[(cbase + q) * 1024 + tok * 8 + 4 * kg] = hv;
      }
    }
  }
  __syncthreads();
}

__global__ __launch_bounds__(THREADS, 2) void siren_kernel(
    const float* __restrict__ coords, const float* __restrict__ bff,
    const float* __restrict__ biasC, const float* __restrict__ b_out,
    const _Float16* __restrict__ wf, const _Float16* __restrict__ wh,
    const _Float16* __restrict__ wo, float* __restrict__ out) {
  extern __shared__ _Float16 hb[];  // chunk-major: [64 chunks][128 tok][8]
  const int tid = threadIdx.x;
  const int t0 = blockIdx.x * TOK;

  // ---- Fourier features: chunks q*4+cb (sin), 16+q*4+cb (cos) ----
  {
    const int t = tid & 127;   // token (wave = 64 consecutive tokens)
    const int q = tid >> 7;    // feature octant: proj j in [q*32, q*32+32)
    const float c0 = coords[(t0 + t) * 3 + 0];
    const float c1 = coords[(t0 + t) * 3 + 1];
    const float c2 = coords[(t0 + t) * 3 + 2];
#pragma unroll
    for (int cb = 0; cb < 4; ++cb) {
      f16x8 sv, cv;
#pragma unroll
      for (int e = 0; e < 8; ++e) {
        const int j = q * 32 + cb * 8 + e;
        float r = fmaf(c0, bff[j], fmaf(c1, bff[128 + j], c2 * bff[256 + j]));
        float fr = __builtin_amdgcn_fractf(r);
        sv[e] = (_Float16)__builtin_amdgcn_sinf(fr);
        cv[e] = (_Float16)__builtin_amdgcn_cosf(fr);
      }
      *(f16x8*)&hb[h_elem(q * 4 + cb, t)] = sv;        // lane-linear store
      *(f16x8*)&hb[h_elem(16 + q * 4 + cb, t)] = cv;
    }
  }
  __syncthreads();

  const int lane = tid & 63;
  const int tk = lane & 31;   // 32x32: A row / B token / C token col
  const int kg = lane >> 5;   // k-group (2 halves of K=16)
  const int m0 = (tid >> 6) * 64;  // wave's 64-feature output slice

  sine_layer<256>(wf, biasC, hb, lane, tk, kg, m0);
#pragma unroll 1
  for (int l = 0; l < 5; ++l)
    sine_layer<512>(wh + l * (512 * 512), biasC + 512 + l * 512, hb, lane, tk,
                    kg, m0);

  // ---- final linear (16x16x32): out[t][0..2], 16 tokens/wave, 8 waves ----
  {
    const int wave = tid >> 6;
    const int lr = lane & 15;
    const int lg = lane >> 4;
    f32x4 acc = {0.f, 0.f, 0.f, 0.f};
#pragma unroll
    for (int ks = 0; ks < 16; ++ks) {
      f16x8 a = *(const f16x8*)&wo[lr * 512 + ks * 32 + lg * 8];
      f16x8 b = *(const f16x8*)&hb[h_elem(ks * 4 + lg, wave * 16 + lr)];
      acc = __builtin_amdgcn_mfma_f32_16x16x32_f16(a, b, acc, 0, 0, 0);
    }
    if (lg == 0) {  // C rows 0..3 in lanes 0..15; out-feature = reg idx
      const int t = t0 + wave * 16 + lr;
      out[t * 3 + 0] = acc[0] + b_out[0];
      out[t * 3 + 1] = acc[1] + b_out[1];
      out[t * 3 + 2] = acc[2] + b_out[2];
    }
  }
}

extern "C" void kernel_launch(void* const* d_in, const int* in_sizes, int n_in,
                              void* d_out, int out_size, void* d_ws,
                              size_t ws_size, hipStream_t stream) {
  const float* coords = (const float*)d_in[0];
  const float* bff    = (const float*)d_in[1];
  const float* Wf     = (const float*)d_in[2];
  const float* bf     = (const float*)d_in[3];
  const float* Wh     = (const float*)d_in[4];
  const float* bh     = (const float*)d_in[5];
  const float* Wo     = (const float*)d_in[6];
  const float* bo     = (const float*)d_in[7];
  float* out = (float*)d_out;

  _Float16* w16 = (_Float16*)d_ws;
  float* biasC = (float*)(w16 + N3);  // 16B-aligned (N3*2 % 16 == 0)

  convert_weights<<<(N3 + NBIAS + 255) / 256, 256, 0, stream>>>(
      Wf, Wh, Wo, bf, bh, w16, biasC);

  const size_t lds_bytes = 64 * 128 * 8 * sizeof(_Float16);  // 131072
  siren_kernel<<<L_TOTAL / TOK, THREADS, lds_bytes, stream>>>(
      coords, bff, biasC, bo, w16, w16 + N1, w16 + N2, out);
}